// Round 7
// baseline (195.992 us; speedup 1.0000x reference)
//
#include <hip/hip_runtime.h>

// Bidirectional GRU (H=32, input=1, B=2048, T=512) + MLP head, fully fused.
//
// Reference takes out[:, -1, :] = concat(h_fwd after T steps, h_bwd after ONE
// step from h0=0 on x[T-1]) -> only the forward scan is sequential; W_hh_b is
// entirely unused.
//
// R18: MFMA recurrence (R16's proven dataflow) + DISTRIBUTED epilogue via
// A-row rotation.
//
// Consolidated model (R8..R17):
//   * VALU family floor: MACs are pinned at ~192 cyc/step/wave (64 f32 MACs
//     per 2 cyc; 96 MACs/lane·step) regardless of dot2/pk_fma (R17: busy 343
//     = R11's 340). R11 (532 cyc/step, 2 rows/wave, full chip) is the VALU
//     optimum. Chip-wide per-step work: ~350K cyc.
//   * MFMA does those MACs in ~15K cyc chip-wide; remaining work = trans 48K
//     + glue ~15K. R16 proved correctness (any consistent A/B K-labeling;
//     D(n=lane&15, m=4q+reg) feeds B) but concentrated 24 trans/wave on 2
//     waves -> 689 cyc/step. Trans must be spread at 1 element/lane.
//   * Rotation trick: wave w loads A-row m from W-row (m&~3)|((m+w)&3), so
//     reg 0 (COMPILE-TIME index) of wave w = column j = 16jh+4q+(w&3).
//     8 waves (2 j-halves x 4 rotations) x 64 lanes = 512 = all (n,j) els of
//     a 16-row tile, exactly 1/lane: 6 trans + ~10 VALU glue + 3 (redundant)
//     MFMAs per wave per step.
//   * h exchange via LDS f16: 1 ds_write_b16 + 2 broadcast ds_read_b64
//     (R16's proven labeling k = 4q+(e&3)+16(e>>2)), parity double-buffer,
//     one __syncthreads per step.
//   * x streams from global (4 MB total, L2-resident; vf4 per 4 steps,
//     prefetched 1 group ahead) -> no 64KB xbuf; LDS ~7 KB.
//   * 128 blocks x 512 thr = 8 waves/block = 2/SIMD on 128 CUs.
//     Per-wave issue ~100 cyc/step vs R11's 340.

typedef float vf4 __attribute__((ext_vector_type(4)));
typedef _Float16 f16;
typedef f16 h4 __attribute__((ext_vector_type(4)));
typedef f16 h8 __attribute__((ext_vector_type(8)));

#define TT 512
#define HH 32
#define HKPAD 36   // hk row stride (f16): 72B rows -> balanced b64 banks
#define OPAD 68    // obuf row stride (floats)

#define LOG2E 1.44269504f

__device__ __forceinline__ float fast_sigm(float a) {   // sigmoid(a)
  return __builtin_amdgcn_rcpf(1.0f + __builtin_amdgcn_exp2f(-LOG2E * a));
}
__device__ __forceinline__ float fast_tanh(float a) {   // tanh(a)
  return __builtin_fmaf(-2.0f,
      __builtin_amdgcn_rcpf(1.0f + __builtin_amdgcn_exp2f(2.0f * LOG2E * a)),
      1.0f);
}

__global__ __launch_bounds__(512)
__attribute__((amdgpu_waves_per_eu(2, 2)))
void gru_bidir_head(const float* __restrict__ X,
                    const float* __restrict__ Wih_f, const float* __restrict__ Whh_f,
                    const float* __restrict__ bih_f, const float* __restrict__ bhh_f,
                    const float* __restrict__ Wih_b,
                    const float* __restrict__ bih_b, const float* __restrict__ bhh_b,
                    const float* __restrict__ W1, const float* __restrict__ b1,
                    const float* __restrict__ W2, const float* __restrict__ b2,
                    float* __restrict__ out)
{
  __shared__ f16   hk[2][16][HKPAD];   // h exchange, f16, parity dbuf (2.3 KB)
  __shared__ float obuf[16][OPAD];     // [row][h_f(32) | h_b(32)] (4.3 KB)

  const int tid  = threadIdx.x;
  const int lane = tid & 63;
  const int w    = tid >> 6;           // wave 0..7
  const int jh   = w >> 2;             // j-half: j in [16jh, 16jh+16)
  const int rw   = w & 3;              // rotation -> reg-0 pick
  const int n    = lane & 15;          // batch row within tile (D/B n-index)
  const int q    = lane >> 4;          // quad 0..3
  const int rb   = blockIdx.x << 4;    // global base row
  const int j    = 16*jh + 4*q + rw;   // this lane's output column (1 el/lane)

  const float s1 = -LOG2E;             // r,z: sigmoid domain (negated)
  const float s2 = 2.0f * LOG2E;       // n: tanh domain

  // --- A-fragments: lane holds A-row m = lane&15; load W-row
  //     16jh + rot(m), rot(m) = (m&~3)|((m+rw)&3)  -> D reg0 = column j.
  //     k-slots per R16's PROVEN labeling: k = {4q..4q+3} U {16+4q..16+4q+3}.
  const int am = 16*jh + ((n & ~3) | ((n + rw) & 3));
  h8 Ar, Az, An;
  {
    const float* p0 = Whh_f + (size_t)(0*HH + am) * HH;   // r gate
    const float* p1 = Whh_f + (size_t)(1*HH + am) * HH;   // z gate
    const float* p2 = Whh_f + (size_t)(2*HH + am) * HH;   // n gate
    const int k1 = 4*q, k2 = 16 + 4*q;
    Ar = (h8){ (f16)(p0[k1]*s1), (f16)(p0[k1+1]*s1), (f16)(p0[k1+2]*s1), (f16)(p0[k1+3]*s1),
               (f16)(p0[k2]*s1), (f16)(p0[k2+1]*s1), (f16)(p0[k2+2]*s1), (f16)(p0[k2+3]*s1) };
    Az = (h8){ (f16)(p1[k1]*s1), (f16)(p1[k1+1]*s1), (f16)(p1[k1+2]*s1), (f16)(p1[k1+3]*s1),
               (f16)(p1[k2]*s1), (f16)(p1[k2+1]*s1), (f16)(p1[k2+2]*s1), (f16)(p1[k2+3]*s1) };
    An = (h8){ (f16)(p2[k1]*s2), (f16)(p2[k1+1]*s2), (f16)(p2[k1+2]*s2), (f16)(p2[k1+3]*s2),
               (f16)(p2[k2]*s2), (f16)(p2[k2+1]*s2), (f16)(p2[k2+2]*s2), (f16)(p2[k2+3]*s2) };
  }

  // --- per-lane seed consts for column j ---
  const float xwr = Wih_f[j] * s1, xwz = Wih_f[HH + j] * s1, xwn = Wih_f[2*HH + j] * s2;
  const float cbr = (bih_f[j]      + bhh_f[j])      * s1;
  const float cbz = (bih_f[HH + j] + bhh_f[HH + j]) * s1;
  const float cbn = bih_f[2*HH + j] * s2;        // n: b_ih term (with x)
  const vf4  Cn  = { bhh_f[2*HH + j] * s2, 0.0f, 0.0f, 0.0f };  // n: b_hh (in MFMA C)

  // --- LDS addresses (loop-invariant) ---
  f16* wp0 = &hk[0][n][j];
  f16* wp1 = &hk[1][n][j];
  const h4* rlo0 = (const h4*)&hk[0][n][4*q];
  const h4* rhi0 = (const h4*)&hk[0][n][16 + 4*q];
  const h4* rlo1 = (const h4*)&hk[1][n][4*q];
  const h4* rhi1 = (const h4*)&hk[1][n][16 + 4*q];

  float h = 0.0f;
  h8 B = {};                                     // h0 = 0
  const float* xr = X + (size_t)(rb + n) * TT;   // x for batch row n (L2-hot)
  vf4 x4 = *(const vf4*)xr;

  #pragma unroll 1
  for (int tg = 0; tg < TT / 4; ++tg) {
    const vf4 x4n = *(const vf4*)(xr + 4 * (tg + 1 < TT/4 ? tg + 1 : tg));

    // hoist x-dependent seeds for the 4 sub-steps (independent of B: these
    // issue inside the barrier/ds-read shadow)
    const float sr0 = __builtin_fmaf(x4.x, xwr, cbr), sz0 = __builtin_fmaf(x4.x, xwz, cbz),
                sn0 = __builtin_fmaf(x4.x, xwn, cbn);
    const float sr1 = __builtin_fmaf(x4.y, xwr, cbr), sz1 = __builtin_fmaf(x4.y, xwz, cbz),
                sn1 = __builtin_fmaf(x4.y, xwn, cbn);
    const float sr2 = __builtin_fmaf(x4.z, xwr, cbr), sz2 = __builtin_fmaf(x4.z, xwz, cbz),
                sn2 = __builtin_fmaf(x4.z, xwn, cbn);
    const float sr3 = __builtin_fmaf(x4.w, xwr, cbr), sz3 = __builtin_fmaf(x4.w, xwz, cbz),
                sn3 = __builtin_fmaf(x4.w, xwn, cbn);

    #pragma unroll
    for (int u = 0; u < 4; ++u) {
      const float sr = (u == 0) ? sr0 : (u == 1) ? sr1 : (u == 2) ? sr2 : sr3;
      const float sz = (u == 0) ? sz0 : (u == 1) ? sz1 : (u == 2) ? sz2 : sz3;
      const float sn = (u == 0) ? sn0 : (u == 1) ? sn1 : (u == 2) ? sn2 : sn3;

      // gh = h @ W_hh.T (+r/z seeds in C): 3 MFMA, only reg 0 consumed
      const vf4 Cr = { sr, 0.0f, 0.0f, 0.0f };
      const vf4 Cz = { sz, 0.0f, 0.0f, 0.0f };
      const vf4 Dr = __builtin_amdgcn_mfma_f32_16x16x32_f16(Ar, B, Cr, 0, 0, 0);
      const vf4 Dz = __builtin_amdgcn_mfma_f32_16x16x32_f16(Az, B, Cz, 0, 0, 0);
      const vf4 Dn = __builtin_amdgcn_mfma_f32_16x16x32_f16(An, B, Cn, 0, 0, 0);

      // epilogue: exactly ONE (row=n, col=j) element per lane
      const float r  = __builtin_amdgcn_rcpf(1.0f + __builtin_amdgcn_exp2f(Dr[0]));
      const float z  = __builtin_amdgcn_rcpf(1.0f + __builtin_amdgcn_exp2f(Dz[0]));
      const float y  = __builtin_fmaf(r, Dn[0], sn);
      const float nn = __builtin_fmaf(-2.0f,
          __builtin_amdgcn_rcpf(1.0f + __builtin_amdgcn_exp2f(y)), 1.0f);
      h = __builtin_fmaf(z, h - nn, nn);         // (1-z)*n + z*h

      // exchange: write own f16, barrier, read B-frag (2x broadcast b64)
      if (u & 1) *wp1 = (f16)h; else *wp0 = (f16)h;
      __syncthreads();
      h4 lo, hi;
      if (u & 1) { lo = *rlo1; hi = *rhi1; } else { lo = *rlo0; hi = *rhi0; }
      B = (h8){ lo[0], lo[1], lo[2], lo[3], hi[0], hi[1], hi[2], hi[3] };
    }
    x4 = x4n;
  }

  // --- publish h_f (fp32): all 512 (n,j) els, each exactly once ---
  obuf[n][j] = h;
  __syncthreads();

  // --- backward (ONE GRU step from h0=0 on x[T-1]) + MLP head, per row ---
  const int g   = tid & 31;
  const int row = tid >> 5;              // 16 groups of 32 lanes = 16 rows
  const float xl  = X[(size_t)(rb + row) * TT + (TT - 1)];
  const float rbv = fast_sigm(__builtin_fmaf(xl, Wih_b[g],      bih_b[g]      + bhh_b[g]));
  const float zbv = fast_sigm(__builtin_fmaf(xl, Wih_b[HH + g], bih_b[HH + g] + bhh_b[HH + g]));
  const float xnb = __builtin_fmaf(xl, Wih_b[2*HH + g], bih_b[2*HH + g]);
  const float nbv = fast_tanh(__builtin_fmaf(rbv, bhh_b[2*HH + g], xnb));
  const float hbv = nbv - zbv * nbv;     // (1-zb)*nb + zb*0
  obuf[row][32 + g] = hbv;
  __builtin_amdgcn_wave_barrier();       // h_b written by same 32-group

  // MLP: sigmoid(W2 @ relu(W1 @ [h_f,h_b] + b1) + b2)
  const int jj = g & 15;                 // lanes 16..31 duplicate
  const vf4* W1r = (const vf4*)(W1 + jj * 64);
  const vf4* hc  = (const vf4*)&obuf[row][0];
  vf4 a4 = W1r[0] * hc[0];
  #pragma unroll
  for (int qq = 1; qq < 16; ++qq)
    a4 = __builtin_elementwise_fma(W1r[qq], hc[qq], a4);
  float acc = b1[jj] + (a4.x + a4.y) + (a4.z + a4.w);
  float h1v = fmaxf(acc, 0.0f) * W2[jj];
  h1v += __shfl_down(h1v, 8, 16);
  h1v += __shfl_down(h1v, 4, 16);
  h1v += __shfl_down(h1v, 2, 16);
  h1v += __shfl_down(h1v, 1, 16);
  if (g == 0) out[rb + row] = fast_sigm(h1v + b2[0]);
}

extern "C" void kernel_launch(void* const* d_in, const int* in_sizes, int n_in,
                              void* d_out, int out_size, void* d_ws, size_t ws_size,
                              hipStream_t stream) {
  const float* X     = (const float*)d_in[0];
  const float* Wih_f = (const float*)d_in[1];
  const float* Whh_f = (const float*)d_in[2];
  const float* bih_f = (const float*)d_in[3];
  const float* bhh_f = (const float*)d_in[4];
  const float* Wih_b = (const float*)d_in[5];
  // d_in[6] = W_hh_b: unused — backward direction runs exactly one step from h0=0.
  const float* bih_b = (const float*)d_in[7];
  const float* bhh_b = (const float*)d_in[8];
  const float* W1    = (const float*)d_in[9];
  const float* b1    = (const float*)d_in[10];
  const float* W2    = (const float*)d_in[11];
  const float* b2    = (const float*)d_in[12];
  float* out = (float*)d_out;

  // 2048 rows / 16 rows per block = 128 blocks x 512 thr (8 waves = 2/SIMD).
  // Wave w: j-half = w>>2, rotation = w&3 -> each lane owns ONE (row, j) el.
  gru_bidir_head<<<128, 512, 0, stream>>>(X, Wih_f, Whh_f, bih_f, bhh_f,
                                          Wih_b, bih_b, bhh_b, W1, b1, W2, b2, out);
}

// Round 8
// 154.638 us; speedup vs baseline: 1.2674x; 1.2674x over previous
//
#include <hip/hip_runtime.h>

// Bidirectional GRU (H=32, input=1, B=2048, T=512) + MLP head, fully fused.
//
// Reference takes out[:, -1, :] = concat(h_fwd after T steps, h_bwd after ONE
// step from h0=0 on x[T-1]) -> only the forward scan is sequential; W_hh_b is
// entirely unused.
//
// R19: MFMA recurrence with SWAPPED operand roles (h in A, W in B) ->
// intra-wave exchange, no block barrier, full chip.
//
// Consolidated model (R8..R18):
//   * VALU family floor ~340 issue cyc/step/wave (R11=R17). MFMA does the
//     MACs ~free, but R16 (concentrated epilogue: 24 trans/wave) and R18
//     (distributed epilogue, cross-wave exchange -> per-step __syncthreads
//     lockstep, stall 336, <=128 CUs) both lose the latency war.
//   * R19 keeps R11's geometry (2 rows/wave, 1024 indep waves, full chip,
//     wave-internal LDS h-exchange ~130 cyc) and R18's 1-el/lane epilogue,
//     by computing D = h @ W^T:
//       - A = h: 2 real rows REPLICATED into 16 m-slots, m=4a+r -> row
//         (a+r)&1. Verified D layout (m=4q+reg, n=lane&15) then gives
//         reg 0 of lane (nh,q) = (row q&1, col nh) for each j-half MFMA.
//       - one v_cndmask on lane>=32 picks lo/hi j-half: each lane owns
//         exactly (row=(lane>>4)&1, j=(lane&15)+16*(lane>>5)).
//       - B = W_hh (constant, 6 h8 frags, exp2-domain pre-scaled).
//       - per-lane seeds ride C reg 0 of BOTH j-half MFMAs (the discarded
//         one adds garbage to a discarded element).
//   * Per wave/step: 6 MFMA + 6 trans + ~15 VALU + 3 DS ~ 125 cyc issue
//     (vs R11 340); chain ~ 130 LDS + 35 MFMA + 110 epi ~ 275 -> chain-bound.
//   * K-labeling k = 4q+(e&3)+16*(e>>2) on BOTH A and B (free but
//     consistent; proven by R16/R18 passing).
//
// Kept from R11: x staged in LDS, vf4 per 4 steps, prefetched; seeds hoisted
// per 4 steps; exp2-domain folding; backward single step + MLP head.

typedef float vf4 __attribute__((ext_vector_type(4)));
typedef _Float16 f16;
typedef f16 h4 __attribute__((ext_vector_type(4)));
typedef f16 h8 __attribute__((ext_vector_type(8)));

#define TT 512
#define HH 32

#define LOG2E 1.44269504f

__device__ __forceinline__ float fast_sigm(float a) {   // sigmoid(a)
  return __builtin_amdgcn_rcpf(1.0f + __builtin_amdgcn_exp2f(-LOG2E * a));
}
__device__ __forceinline__ float fast_tanh(float a) {   // tanh(a)
  return __builtin_fmaf(-2.0f,
      __builtin_amdgcn_rcpf(1.0f + __builtin_amdgcn_exp2f(2.0f * LOG2E * a)),
      1.0f);
}

__global__ __launch_bounds__(256)
__attribute__((amdgpu_waves_per_eu(1, 1)))
void gru_bidir_head(const float* __restrict__ X,
                    const float* __restrict__ Wih_f, const float* __restrict__ Whh_f,
                    const float* __restrict__ bih_f, const float* __restrict__ bhh_f,
                    const float* __restrict__ Wih_b,
                    const float* __restrict__ bih_b, const float* __restrict__ bhh_b,
                    const float* __restrict__ W1, const float* __restrict__ b1,
                    const float* __restrict__ W2, const float* __restrict__ b2,
                    float* __restrict__ out)
{
  __shared__ float xbuf[8][TT];        // staged input rows (16 KB)
  __shared__ f16   hbuf[4][2][HH];     // per-wave h exchange [wave][row][j] (512 B)
  __shared__ float obuf[8][64];        // [row][h_f(32) | h_b(32)] (2 KB)

  const int tid  = threadIdx.x;
  const int lane = tid & 63;
  const int wid  = tid >> 6;           // wave 0..3; serves block rows {2wid, 2wid+1}
  const int nh   = lane & 15;          // MFMA n-index
  const int q    = lane >> 4;          // quad 0..3
  const int p    = q & 1;              // owned element's row parity
  const int hsel = lane >> 5;          // owned element's j-half
  const int j    = nh + 16 * hsel;     // owned output column
  const int rs   = 2 * wid + p;        // owned element's local row (0..7)

  // --- stage 8 rows of X into LDS (R11 pattern: 32-lane groups) ---
  const int g32 = tid & 31, rsS = tid >> 5;
  const vf4* Xr4 = (const vf4*)(X + (size_t)((blockIdx.x << 3) + rsS) * TT);
  vf4* xb4 = (vf4*)&xbuf[rsS][0];
  #pragma unroll
  for (int qq = 0; qq < 4; ++qq) xb4[g32 + 32 * qq] = Xr4[g32 + 32 * qq];

  const float s1 = -LOG2E;             // r,z: sigmoid domain (negated)
  const float s2 = 2.0f * LOG2E;       // n: tanh domain

  // --- B-fragments: W_hh, constant. Gate G, j-half F: lane (nh,q) holds
  //     B[k][n=nh] = W[G*32 + nh + 16F][k], k in {4q..4q+3, 16+4q..16+4q+3} ---
#define LDB(P, G, F, S) h8 P; { \
    const float* wr = Whh_f + (size_t)((G)*HH + nh + 16*(F)) * HH; \
    const int k1 = 4*q, k2 = 16 + 4*q; \
    P = (h8){ (f16)(wr[k1]*(S)), (f16)(wr[k1+1]*(S)), (f16)(wr[k1+2]*(S)), (f16)(wr[k1+3]*(S)), \
              (f16)(wr[k2]*(S)), (f16)(wr[k2+1]*(S)), (f16)(wr[k2+2]*(S)), (f16)(wr[k2+3]*(S)) }; }
  LDB(Br0, 0, 0, s1); LDB(Br1, 0, 1, s1);
  LDB(Bz0, 1, 0, s1); LDB(Bz1, 1, 1, s1);
  LDB(Bn0, 2, 0, s2); LDB(Bn1, 2, 1, s2);

  // --- per-lane seed consts for the owned column j ---
  const float xwr = Wih_f[j] * s1, xwz = Wih_f[HH + j] * s1, xwn = Wih_f[2*HH + j] * s2;
  const float cbr = (bih_f[j]      + bhh_f[j])      * s1;
  const float cbz = (bih_f[HH + j] + bhh_f[HH + j]) * s1;
  const float cbn = bih_f[2*HH + j] * s2;        // n: b_ih term (with x)
  const float cbh = bhh_f[2*HH + j] * s2;        // n: b_hh term (inside r*(.)) -> C
  const vf4 Ch = { cbh, 0.0f, 0.0f, 0.0f };

  // --- A-frag LDS addresses: lane is A-row m=nh; holds h[rowA][k-slots(q)],
  //     rowA per the replication pattern m=4a+r -> row (a+r)&1 ---
  const int rowA = ((nh >> 2) + (nh & 3)) & 1;
  const h4* Alo = (const h4*)&hbuf[wid][rowA][4*q];
  const h4* Ahi = (const h4*)&hbuf[wid][rowA][16 + 4*q];
  f16* hwp = &hbuf[wid][p][j];         // own element's slot

  float h = 0.0f;
  *hwp = (f16)0.0f;                    // zero-init exchange buffer
  __builtin_amdgcn_wave_barrier();

  const vf4* xv = (const vf4*)&xbuf[rs][0];
  vf4 x4 = xv[0];

  #pragma unroll 1
  for (int tg = 0; tg < TT / 4; ++tg) {
    const vf4 x4n = xv[tg + 1 < TT / 4 ? tg + 1 : tg];   // off critical path

    // hoist x-dependent seeds for the 4 sub-steps (own row's x, own j)
    const float sr0 = __builtin_fmaf(x4.x, xwr, cbr), sz0 = __builtin_fmaf(x4.x, xwz, cbz),
                sn0 = __builtin_fmaf(x4.x, xwn, cbn);
    const float sr1 = __builtin_fmaf(x4.y, xwr, cbr), sz1 = __builtin_fmaf(x4.y, xwz, cbz),
                sn1 = __builtin_fmaf(x4.y, xwn, cbn);
    const float sr2 = __builtin_fmaf(x4.z, xwr, cbr), sz2 = __builtin_fmaf(x4.z, xwz, cbz),
                sn2 = __builtin_fmaf(x4.z, xwn, cbn);
    const float sr3 = __builtin_fmaf(x4.w, xwr, cbr), sz3 = __builtin_fmaf(x4.w, xwz, cbz),
                sn3 = __builtin_fmaf(x4.w, xwn, cbn);

    #pragma unroll
    for (int u = 0; u < 4; ++u) {
      const float sr = (u == 0) ? sr0 : (u == 1) ? sr1 : (u == 2) ? sr2 : sr3;
      const float sz = (u == 0) ? sz0 : (u == 1) ? sz1 : (u == 2) ? sz2 : sz3;
      const float sn = (u == 0) ? sn0 : (u == 1) ? sn1 : (u == 2) ? sn2 : sn3;

      // A-frag: this wave's 2 h-rows, replicated interleave (2x ds_read_b64)
      const h4 alo = *Alo, ahi = *Ahi;
      const h8 A = (h8){alo[0], alo[1], alo[2], alo[3],
                        ahi[0], ahi[1], ahi[2], ahi[3]};

      // D = h @ W^T (+ per-lane seeds in C reg0): 6 MFMA, reg0 consumed
      const vf4 Cr = { sr, 0.0f, 0.0f, 0.0f };
      const vf4 Cz = { sz, 0.0f, 0.0f, 0.0f };
      const vf4 Dr0 = __builtin_amdgcn_mfma_f32_16x16x32_f16(A, Br0, Cr, 0, 0, 0);
      const vf4 Dr1 = __builtin_amdgcn_mfma_f32_16x16x32_f16(A, Br1, Cr, 0, 0, 0);
      const vf4 Dz0 = __builtin_amdgcn_mfma_f32_16x16x32_f16(A, Bz0, Cz, 0, 0, 0);
      const vf4 Dz1 = __builtin_amdgcn_mfma_f32_16x16x32_f16(A, Bz1, Cz, 0, 0, 0);
      const vf4 Dn0 = __builtin_amdgcn_mfma_f32_16x16x32_f16(A, Bn0, Ch, 0, 0, 0);
      const vf4 Dn1 = __builtin_amdgcn_mfma_f32_16x16x32_f16(A, Bn1, Ch, 0, 0, 0);

      // select own j-half: element (row p, col j), seeds already included
      const float ar = hsel ? Dr1[0] : Dr0[0];
      const float az = hsel ? Dz1[0] : Dz0[0];
      const float an = hsel ? Dn1[0] : Dn0[0];

      // epilogue: exactly ONE element per lane
      const float r  = __builtin_amdgcn_rcpf(1.0f + __builtin_amdgcn_exp2f(ar));
      const float z  = __builtin_amdgcn_rcpf(1.0f + __builtin_amdgcn_exp2f(az));
      const float y  = __builtin_fmaf(r, an, sn);
      const float nn = __builtin_fmaf(-2.0f,
          __builtin_amdgcn_rcpf(1.0f + __builtin_amdgcn_exp2f(y)), 1.0f);
      h = __builtin_fmaf(z, h - nn, nn);         // (1-z)*n + z*h

      *hwp = (f16)h;                             // v_cvt + ds_write_b16
      __builtin_amdgcn_wave_barrier();           // wave-synchronous ordering
    }
    x4 = x4n;
  }

  // --- publish h_f (fp32): each lane writes its (row, j) element once ---
  obuf[rs][j] = h;
  __syncthreads();

  // --- backward direction: exactly ONE GRU step from h0=0 on x[T-1] ---
  const float xl  = xbuf[rsS][TT - 1];
  const float rbv = fast_sigm(__builtin_fmaf(xl, Wih_b[g32],      bih_b[g32]      + bhh_b[g32]));
  const float zbv = fast_sigm(__builtin_fmaf(xl, Wih_b[HH + g32], bih_b[HH + g32] + bhh_b[HH + g32]));
  const float xnb = __builtin_fmaf(xl, Wih_b[2*HH + g32], bih_b[2*HH + g32]);
  const float nbv = fast_tanh(__builtin_fmaf(rbv, bhh_b[2*HH + g32], xnb));
  const float hbv = nbv - zbv * nbv;             // (1-zb)*nb + zb*0

  obuf[rsS][32 + g32] = hbv;                     // h_b
  __builtin_amdgcn_wave_barrier();

  // --- MLP head: sigmoid(W2 @ relu(W1 @ [h_f,h_b] + b1) + b2) ---
  const int jj = g32 & 15;                       // lanes 16..31 duplicate
  const vf4* W1r = (const vf4*)(W1 + jj * 64);
  const vf4* hc  = (const vf4*)&obuf[rsS][0];
  vf4 a4 = W1r[0] * hc[0];
  #pragma unroll
  for (int qq = 1; qq < 16; ++qq)
    a4 = __builtin_elementwise_fma(W1r[qq], hc[qq], a4);
  float acc = b1[jj] + (a4.x + a4.y) + (a4.z + a4.w);
  float h1v = fmaxf(acc, 0.0f) * W2[jj];
  h1v += __shfl_down(h1v, 8, 16);
  h1v += __shfl_down(h1v, 4, 16);
  h1v += __shfl_down(h1v, 2, 16);
  h1v += __shfl_down(h1v, 1, 16);
  if (g32 == 0) out[(blockIdx.x << 3) + rsS] = fast_sigm(h1v + b2[0]);
}

extern "C" void kernel_launch(void* const* d_in, const int* in_sizes, int n_in,
                              void* d_out, int out_size, void* d_ws, size_t ws_size,
                              hipStream_t stream) {
  const float* X     = (const float*)d_in[0];
  const float* Wih_f = (const float*)d_in[1];
  const float* Whh_f = (const float*)d_in[2];
  const float* bih_f = (const float*)d_in[3];
  const float* bhh_f = (const float*)d_in[4];
  const float* Wih_b = (const float*)d_in[5];
  // d_in[6] = W_hh_b: unused — backward direction runs exactly one step from h0=0.
  const float* bih_b = (const float*)d_in[7];
  const float* bhh_b = (const float*)d_in[8];
  const float* W1    = (const float*)d_in[9];
  const float* b1    = (const float*)d_in[10];
  const float* W2    = (const float*)d_in[11];
  const float* b2    = (const float*)d_in[12];
  float* out = (float*)d_out;

  // 2048 rows / 8 rows per 256-thread block = 256 blocks = 1 block/CU,
  // 1024 independent waves = 1 wave/SIMD, full chip. No block barrier in the
  // recurrence loop: each wave's exchange is wave-internal LDS.
  gru_bidir_head<<<256, 256, 0, stream>>>(X, Wih_f, Whh_f, bih_f, bhh_f,
                                          Wih_b, bih_b, bhh_b, W1, b1, W2, b2, out);
}